// Round 9
// baseline (179.786 us; speedup 1.0000x reference)
//
#include <hip/hip_runtime.h>
#include <hip/hip_fp16.h>

// Geo_GCN, zero-global-atomic pipeline + W pulled through the edge sum:
//   out[n] = b + dinv[n] * sum_e w_e * y[c_e],   y = x @ W^T  (fp16)
// Build: hist2 -> scan -> scatcol -> coldinv -> scatter1 -> sort2
// Then:  ygemm (W in VGPRs, y fp16, aliases edges8) -> gather (register accum,
//        8 edges in flight/wave, no LDS, direct store).

constexpr int NN   = 100000;
constexpr int NE   = 1600000;
constexpr int D    = 64;
constexpr int NBUK = (NN + 63) / 64;          // 1563 buckets of 64 nodes
constexpr int HB   = 256;                     // chunk-parallel grid
constexpr int HT   = 1024;
constexpr int CHUNK = NE / HB;                // 6250 (exact)
constexpr int NSC  = NBUK * HB;               // 400128 per hist
constexpr int NSC2 = 2 * NSC;                 // row + col hists, one scan
constexpr int SCB  = 1024;
constexpr int SCG  = (NSC2 + SCB - 1) / SCB;  // 782

// ---- pass 1: both bucket histograms in LDS; no global atomics ----
__global__ void __launch_bounds__(HT)
hist2_kernel(const int* __restrict__ row, const int* __restrict__ col,
             int* __restrict__ hist) {
    __shared__ int hr[NBUK], hc[NBUK];
    const int t = threadIdx.x;
    for (int i = t; i < NBUK; i += HT) { hr[i] = 0; hc[i] = 0; }
    __syncthreads();
    const int e0 = blockIdx.x * CHUNK;
    for (int e = e0 + t; e < e0 + CHUNK; e += HT) {
        atomicAdd(&hr[row[e] >> 6], 1);
        atomicAdd(&hc[col[e] >> 6], 1);
    }
    __syncthreads();
    for (int i = t; i < NBUK; i += HT) {
        hist[i * HB + blockIdx.x]       = hr[i];
        hist[NSC + i * HB + blockIdx.x] = hc[i];
    }
}

// ---- combined exclusive scan over hist[NSC2] ----
__global__ void scanpart_kernel(const int* __restrict__ a, int* __restrict__ bsum) {
    __shared__ int red[16];
    const int t = threadIdx.x;
    const int i = blockIdx.x * SCB + t;
    int s = (i < NSC2) ? a[i] : 0;
    #pragma unroll
    for (int o = 1; o < 64; o <<= 1) s += __shfl_xor(s, o);
    if ((t & 63) == 0) red[t >> 6] = s;
    __syncthreads();
    if (t < 16) {
        int ss = red[t];
        #pragma unroll
        for (int o = 1; o < 16; o <<= 1) ss += __shfl_xor(ss, o);
        if (t == 0) bsum[blockIdx.x] = ss;
    }
}

__global__ void scanblk_kernel(const int* __restrict__ bsum, int* __restrict__ boff) {
    __shared__ int wsum[16], wsum2[16];
    const int t = threadIdx.x;              // 1024
    const int lane = t & 63;
    const int w = t >> 6;
    const int v = (t < SCG) ? bsum[t] : 0;
    int s = v;
    #pragma unroll
    for (int o = 1; o < 64; o <<= 1) { int u = __shfl_up(s, o); if (lane >= o) s += u; }
    if (lane == 63) wsum[w] = s;
    __syncthreads();
    if (t < 16) {
        int ss = wsum[t];
        #pragma unroll
        for (int o = 1; o < 16; o <<= 1) { int u = __shfl_up(ss, o); if (t >= o) ss += u; }
        wsum2[t] = ss;
    }
    __syncthreads();
    const int excl = (w ? wsum2[w - 1] : 0) + (s - v);
    if (t < SCG) boff[t] = excl;
}

// in-place: hist -> exclusive offsets (each thread touches only its own element)
__global__ void scanfinal_kernel(int* __restrict__ a, const int* __restrict__ boff) {
    __shared__ int wsum[16], wsum2[16];
    const int t = threadIdx.x;
    const int i = blockIdx.x * SCB + t;
    const int lane = t & 63;
    const int w = t >> 6;
    const int v = (i < NSC2) ? a[i] : 0;
    int s = v;
    #pragma unroll
    for (int o = 1; o < 64; o <<= 1) { int u = __shfl_up(s, o); if (lane >= o) s += u; }
    if (lane == 63) wsum[w] = s;
    __syncthreads();
    if (t < 16) {
        int ss = wsum[t];
        #pragma unroll
        for (int o = 1; o < 16; o <<= 1) { int u = __shfl_up(ss, o); if (t >= o) ss += u; }
        wsum2[t] = ss;
    }
    __syncthreads();
    const int excl = boff[blockIdx.x] + (w ? wsum2[w - 1] : 0) + (s - v);
    if (i < NSC2) a[i] = excl;
}

// ---- col digits into col-buckets (LDS cursors) ----
__global__ void __launch_bounds__(HT)
scatcol_kernel(const int* __restrict__ col, const int* __restrict__ hoff,
               unsigned char* __restrict__ colidx) {
    __shared__ int cur[NBUK];
    const int t = threadIdx.x;
    for (int i = t; i < NBUK; i += HT) cur[i] = hoff[NSC + i * HB + blockIdx.x] - NE;
    __syncthreads();
    const int e0 = blockIdx.x * CHUNK;
    for (int e = e0 + t; e < e0 + CHUNK; e += HT) {
        const int c = col[e];
        const int pos = atomicAdd(&cur[c >> 6], 1);
        colidx[pos] = (unsigned char)(c & 63);
    }
}

// ---- per-bucket exact degree count -> dinv ----
__global__ void __launch_bounds__(256)
coldinv_kernel(const int* __restrict__ hoff, const unsigned char* __restrict__ colidx,
               float* __restrict__ dinv) {
    __shared__ int cnt[64];
    const int t = threadIdx.x;
    const int b = blockIdx.x;
    if (t < 64) cnt[t] = 0;
    __syncthreads();
    const int s0 = hoff[NSC + b * HB] - NE;
    const int s1 = (b + 1 < NBUK) ? (hoff[NSC + (b + 1) * HB] - NE) : NE;
    for (int k = s0 + t; k < s1; k += 256) atomicAdd(&cnt[colidx[k]], 1);
    __syncthreads();
    if (t < 64) {
        const int n = b * 64 + t;
        if (n < NN) {
            const int d = cnt[t];
            dinv[n] = (d > 0) ? rsqrtf((float)d) : 0.0f;
        }
    }
}

// ---- edges into row-buckets; weight = 15-bit fp of exp(-d^2)*dinv[c] ----
__global__ void __launch_bounds__(HT)
scatter1_kernel(const int* __restrict__ row, const int* __restrict__ col,
                const float* __restrict__ dist, const float* __restrict__ dinv,
                const int* __restrict__ hoff, int2* __restrict__ edges8) {
    __shared__ int cur[NBUK];
    const int t = threadIdx.x;
    for (int i = t; i < NBUK; i += HT) cur[i] = hoff[i * HB + blockIdx.x];
    __syncthreads();
    const int e0 = blockIdx.x * CHUNK;
    for (int e = e0 + t; e < e0 + CHUNK; e += HT) {
        const int r = row[e];
        const int c = col[e];
        const float dv = dist[e];
        const float wv = expf(-dv * dv) * dinv[c];               // (0, 1]
        const unsigned w15 = (unsigned)(wv * 32767.0f + 0.5f);
        const int pos = atomicAdd(&cur[r >> 6], 1);              // LDS atomic
        edges8[pos] = make_int2((int)((w15 << 17) | (unsigned)c), r);
    }
}

// ---- per-bucket counting sort by r&63 -> node-grouped 4B edges + rowstart ----
__global__ void __launch_bounds__(256)
sort2_kernel(const int* __restrict__ hoff, const int2* __restrict__ edges8,
             unsigned* __restrict__ edges4, int* __restrict__ rowstart) {
    __shared__ int cnt[64], cur[64];
    const int t = threadIdx.x;
    const int b = blockIdx.x;
    if (t < 64) cnt[t] = 0;
    __syncthreads();
    const int s0 = hoff[b * HB];
    const int s1 = (b + 1 < NBUK) ? hoff[(b + 1) * HB] : NE;
    for (int k = s0 + t; k < s1; k += 256) atomicAdd(&cnt[edges8[k].y & 63], 1);
    __syncthreads();
    if (t < 64) {
        const int v = cnt[t];
        int s = v;
        #pragma unroll
        for (int o = 1; o < 64; o <<= 1) { int u = __shfl_up(s, o); if (t >= o) s += u; }
        const int excl = s - v;
        cur[t] = excl;
        rowstart[b * 64 + t] = s0 + excl;      // start of node b*64+t
        if (b == NBUK - 1 && t == 63) rowstart[NBUK * 64] = NE;
    }
    __syncthreads();
    for (int k = s0 + t; k < s1; k += 256) {
        const int2 m = edges8[k];
        const int pos = s0 + atomicAdd(&cur[m.y & 63], 1);
        edges4[pos] = (unsigned)m.x;
    }
}

// ---- y = x @ W^T, stored fp16. W row j=lane held in 64 VGPRs; x row is a
// wave-uniform broadcast load. One wave per node, grid-stride. ----
__global__ void __launch_bounds__(256)
ygemm_kernel(const float* __restrict__ x, const float* __restrict__ W,
             __half* __restrict__ y) {
    const int lane = threadIdx.x & 63;
    float wr[64];
    #pragma unroll
    for (int k4 = 0; k4 < 16; ++k4) {
        const float4 w4 = *reinterpret_cast<const float4*>(W + (size_t)lane * 64 + k4 * 4);
        wr[k4 * 4 + 0] = w4.x; wr[k4 * 4 + 1] = w4.y;
        wr[k4 * 4 + 2] = w4.z; wr[k4 * 4 + 3] = w4.w;
    }
    const int wid = (blockIdx.x * 256 + threadIdx.x) >> 6;
    const int nw = (gridDim.x * 256) >> 6;
    for (int n = wid; n < NN; n += nw) {
        const float* xp = x + (size_t)n * 64;
        float acc = 0.0f;
        #pragma unroll
        for (int k4 = 0; k4 < 16; ++k4) {
            const float4 xv = *reinterpret_cast<const float4*>(xp + k4 * 4);  // broadcast
            acc += xv.x * wr[k4 * 4 + 0] + xv.y * wr[k4 * 4 + 1]
                 + xv.z * wr[k4 * 4 + 2] + xv.w * wr[k4 * 4 + 3];
        }
        y[(size_t)n * 64 + lane] = __float2half(acc);
    }
}

// ---- per-node register gather over y (8 edges in flight/wave), direct store ----
__global__ void __launch_bounds__(256)
gather_kernel(const int* __restrict__ rowstart, const unsigned* __restrict__ edges4,
              const float* __restrict__ dinvg, const __half* __restrict__ y,
              const float* __restrict__ bias, float* __restrict__ out) {
    const int t = threadIdx.x;
    const int lane = t & 63;
    const int wv = t >> 6;
    const int sub = lane >> 3;        // which of 8 concurrent edges
    const int ch8 = (lane & 7) << 3;  // 8 channels per lane
    constexpr float WSCL = 1.0f / 32767.0f;
    const float4 b0 = *reinterpret_cast<const float4*>(bias + ch8);
    const float4 b1 = *reinterpret_cast<const float4*>(bias + ch8 + 4);

    const int nwaves = gridDim.x * 4;
    for (int n = blockIdx.x * 4 + wv; n < NN; n += nwaves) {
        const int s0 = rowstart[n];
        const int s1 = rowstart[n + 1];
        float a0 = 0.f, a1 = 0.f, a2 = 0.f, a3 = 0.f;
        float a4 = 0.f, a5 = 0.f, a6 = 0.f, a7 = 0.f;
        for (int p0 = s0; p0 < s1; p0 += 8) {
            const int pp = p0 + sub;
            const int ppc = (pp < s1) ? pp : (s1 - 1);    // clamped -> valid load
            const unsigned m = edges4[ppc];
            const int c = (int)(m & 0x1FFFFu);
            float wgt = (float)(m >> 17) * WSCL;
            wgt = (pp < s1) ? wgt : 0.0f;
            const float4 raw = *reinterpret_cast<const float4*>(y + (size_t)c * 64 + ch8);
            const __half2* h2 = reinterpret_cast<const __half2*>(&raw);
            const float2 f0 = __half22float2(h2[0]);
            const float2 f1 = __half22float2(h2[1]);
            const float2 f2 = __half22float2(h2[2]);
            const float2 f3 = __half22float2(h2[3]);
            a0 += wgt * f0.x; a1 += wgt * f0.y; a2 += wgt * f1.x; a3 += wgt * f1.y;
            a4 += wgt * f2.x; a5 += wgt * f2.y; a6 += wgt * f3.x; a7 += wgt * f3.y;
        }
        #pragma unroll
        for (int o = 8; o < 64; o <<= 1) {
            a0 += __shfl_xor(a0, o); a1 += __shfl_xor(a1, o);
            a2 += __shfl_xor(a2, o); a3 += __shfl_xor(a3, o);
            a4 += __shfl_xor(a4, o); a5 += __shfl_xor(a5, o);
            a6 += __shfl_xor(a6, o); a7 += __shfl_xor(a7, o);
        }
        if (sub == 0) {
            const float dn = dinvg[n];
            const float4 o0 = make_float4(b0.x + dn * a0, b0.y + dn * a1,
                                          b0.z + dn * a2, b0.w + dn * a3);
            const float4 o1 = make_float4(b1.x + dn * a4, b1.y + dn * a5,
                                          b1.z + dn * a6, b1.w + dn * a7);
            float* op = out + (size_t)n * 64 + ch8;
            *reinterpret_cast<float4*>(op)     = o0;
            *reinterpret_cast<float4*>(op + 4) = o1;
        }
    }
}

extern "C" void kernel_launch(void* const* d_in, const int* in_sizes, int n_in,
                              void* d_out, int out_size, void* d_ws, size_t ws_size,
                              hipStream_t stream) {
    const float* x    = (const float*)d_in[0];
    const int*   ei   = (const int*)d_in[1];
    const float* dist = (const float*)d_in[2];
    const float* W    = (const float*)d_in[3];
    const float* b    = (const float*)d_in[4];
    float* out = (float*)d_out;

    const int* row = ei;
    const int* col = ei + NE;

    // workspace (~24.9 MB; 26 MB proven safe). y (12.8 MB) ALIASES edges8:
    // edges8 is dead after sort2, ygemm runs after sort2 on the same stream.
    int2*     edges8   = (int2*)d_ws;                       // NE int2 (12.8 MB)
    __half*   y        = (__half*)d_ws;                     // NN*64 half (12.8 MB)
    unsigned* edges4   = (unsigned*)(edges8 + NE);          // NE u32 (6.4 MB)
    int*      hist     = (int*)(edges4 + NE);               // NSC2 (3.2 MB) -> hoff in place
    int*      rowstart = hist + NSC2;                       // NBUK*64+1 (~400 KB)
    float*    dinv     = (float*)(rowstart + NBUK * 64 + 1);// NN
    int*      bsum     = (int*)(dinv + NN);                 // SCG
    int*      boff     = bsum + SCG;                        // SCG
    unsigned char* colidx = (unsigned char*)(boff + SCG);   // NE bytes (1.6 MB)

    hist2_kernel    <<<HB, HT, 0, stream>>>(row, col, hist);
    scanpart_kernel <<<SCG, SCB, 0, stream>>>(hist, bsum);
    scanblk_kernel  <<<1, 1024, 0, stream>>>(bsum, boff);
    scanfinal_kernel<<<SCG, SCB, 0, stream>>>(hist, boff);
    scatcol_kernel  <<<HB, HT, 0, stream>>>(col, hist, colidx);
    coldinv_kernel  <<<NBUK, 256, 0, stream>>>(hist, colidx, dinv);
    scatter1_kernel <<<HB, HT, 0, stream>>>(row, col, dist, dinv, hist, edges8);
    sort2_kernel    <<<NBUK, 256, 0, stream>>>(hist, edges8, edges4, rowstart);
    ygemm_kernel    <<<2048, 256, 0, stream>>>(x, W, y);
    gather_kernel   <<<4096, 256, 0, stream>>>(rowstart, edges4, dinv, y, b, out);
}